// Round 1
// baseline (572.385 us; speedup 1.0000x reference)
//
#include <hip/hip_runtime.h>

#define N_NODES 100000
#define N_EDGES 3200000
#define D_FEAT 128
#define HIDDEN 16
#define NCLS 8

// -------- workspace layout (floats) --------
// deg   (uint) [0,   N)
// dis          [N,  2N)
// hd1          [2N, 18N)   N x 16
// agg1         [18N,34N)   N x 16
// hd2          [34N,42N)   N x 8
// agg2         [42N,50N)   N x 8

__global__ void k_deg_init(unsigned* __restrict__ deg) {
    int i = blockIdx.x * blockDim.x + threadIdx.x;
    if (i < N_NODES) deg[i] = 1u;            // self-loop
}

__global__ void k_deg_count(const int* __restrict__ dst, unsigned* __restrict__ deg) {
    int i = blockIdx.x * blockDim.x + threadIdx.x;
    if (i < N_EDGES) atomicAdd(&deg[dst[i]], 1u);
}

__global__ void k_dis(const unsigned* __restrict__ deg, float* __restrict__ dis) {
    int i = blockIdx.x * blockDim.x + threadIdx.x;
    if (i < N_NODES) dis[i] = rsqrtf((float)deg[i]);
}

// x @ W1, pre-scaled by dis[node]; writes hd1 and initializes agg1 (self-loop term)
__global__ __launch_bounds__(256) void k_gemm1(const float* __restrict__ x,
                                               const float* __restrict__ W1,
                                               const float* __restrict__ dis,
                                               float* __restrict__ hd1,
                                               float* __restrict__ agg1) {
    __shared__ float sW[D_FEAT * HIDDEN];   // 8 KB  [k][j]
    __shared__ float sx[64][132];           // 33 KB, pad 132 to break bank conflicts
    int tid = threadIdx.x;
    for (int t = tid; t < D_FEAT * HIDDEN; t += 256) sW[t] = W1[t];

    int node0 = blockIdx.x * 64;
    // cooperative coalesced load of 64 rows of x
    #pragma unroll
    for (int it = 0; it < 8; ++it) {
        int lin = it * 256 + tid;           // 0..2047 -> (row, float4-col)
        int r   = lin >> 5;
        int c4  = lin & 31;
        int row = node0 + r;
        float4 v = make_float4(0.f, 0.f, 0.f, 0.f);
        if (row < N_NODES)
            v = *(const float4*)(x + (size_t)row * D_FEAT + c4 * 4);
        *(float4*)(&sx[r][c4 * 4]) = v;
    }
    __syncthreads();

    int lr   = tid >> 2;                    // local row (0..63)
    int node = node0 + lr;
    int f0   = (tid & 3) * 4;               // 4 output feats per thread
    if (node >= N_NODES) return;

    float a0 = 0.f, a1 = 0.f, a2 = 0.f, a3 = 0.f;
    #pragma unroll
    for (int k = 0; k < D_FEAT; ++k) {
        float xv = sx[lr][k];
        a0 += xv * sW[k * HIDDEN + f0 + 0];
        a1 += xv * sW[k * HIDDEN + f0 + 1];
        a2 += xv * sW[k * HIDDEN + f0 + 2];
        a3 += xv * sW[k * HIDDEN + f0 + 3];
    }
    float s = dis[node];
    float4 o = make_float4(a0 * s, a1 * s, a2 * s, a3 * s);
    *(float4*)(hd1 + (size_t)node * HIDDEN + f0) = o;
    *(float4*)(agg1 + (size_t)node * HIDDEN + f0) = o;   // self-loop init
}

// one thread per (edge, feature): agg[dst][j] += hd[src][j]
__global__ void k_scatter16(const int* __restrict__ src, const int* __restrict__ dst,
                            const float* __restrict__ hd, float* __restrict__ agg) {
    long long g = (long long)blockIdx.x * blockDim.x + threadIdx.x;
    if (g >= (long long)N_EDGES * HIDDEN) return;
    int e = (int)(g >> 4);
    int j = (int)(g & 15);
    atomicAdd(&agg[(size_t)dst[e] * HIDDEN + j], hd[(size_t)src[e] * HIDDEN + j]);
}

__global__ void k_scatter8(const int* __restrict__ src, const int* __restrict__ dst,
                           const float* __restrict__ hd, float* __restrict__ agg) {
    long long g = (long long)blockIdx.x * blockDim.x + threadIdx.x;
    if (g >= (long long)N_EDGES * NCLS) return;
    int e = (int)(g >> 3);
    int j = (int)(g & 7);
    atomicAdd(&agg[(size_t)dst[e] * NCLS + j], hd[(size_t)src[e] * NCLS + j]);
}

// out1 = relu(dis*agg1 + b1); hd2 = (out1 @ W2) * dis; agg2 init = hd2
__global__ __launch_bounds__(256) void k_layer2(const float* __restrict__ agg1,
                                                const float* __restrict__ dis,
                                                const float* __restrict__ b1,
                                                const float* __restrict__ W2,
                                                float* __restrict__ hd2,
                                                float* __restrict__ agg2) {
    __shared__ float sW[HIDDEN * NCLS];     // 128 floats
    __shared__ float sb[HIDDEN];
    int tid = threadIdx.x;
    if (tid < HIDDEN * NCLS) sW[tid] = W2[tid];
    if (tid < HIDDEN)        sb[tid] = b1[tid];
    __syncthreads();

    int i = blockIdx.x * 256 + tid;
    if (i >= N_NODES) return;
    float s = dis[i];

    float h[HIDDEN];
    const float4* ap = (const float4*)(agg1 + (size_t)i * HIDDEN);
    #pragma unroll
    for (int q = 0; q < 4; ++q) {
        float4 a = ap[q];
        h[q * 4 + 0] = fmaxf(s * a.x + sb[q * 4 + 0], 0.f);
        h[q * 4 + 1] = fmaxf(s * a.y + sb[q * 4 + 1], 0.f);
        h[q * 4 + 2] = fmaxf(s * a.z + sb[q * 4 + 2], 0.f);
        h[q * 4 + 3] = fmaxf(s * a.w + sb[q * 4 + 3], 0.f);
    }
    float o[NCLS];
    #pragma unroll
    for (int k = 0; k < NCLS; ++k) o[k] = 0.f;
    #pragma unroll
    for (int j = 0; j < HIDDEN; ++j) {
        float hv = h[j];
        #pragma unroll
        for (int k = 0; k < NCLS; ++k) o[k] += hv * sW[j * NCLS + k];
    }
    float4 o0 = make_float4(o[0] * s, o[1] * s, o[2] * s, o[3] * s);
    float4 o1 = make_float4(o[4] * s, o[5] * s, o[6] * s, o[7] * s);
    float4* h2 = (float4*)(hd2  + (size_t)i * NCLS);
    float4* a2 = (float4*)(agg2 + (size_t)i * NCLS);
    h2[0] = o0; h2[1] = o1;
    a2[0] = o0; a2[1] = o1;     // self-loop init
}

// logits = dis*agg2 + b2; out = log_softmax(logits)
__global__ void k_final(const float* __restrict__ agg2, const float* __restrict__ dis,
                        const float* __restrict__ b2, float* __restrict__ out) {
    int i = blockIdx.x * blockDim.x + threadIdx.x;
    if (i >= N_NODES) return;
    float s = dis[i];
    float l[NCLS];
    const float4* ap = (const float4*)(agg2 + (size_t)i * NCLS);
    float4 a0 = ap[0], a1 = ap[1];
    l[0] = s * a0.x + b2[0]; l[1] = s * a0.y + b2[1];
    l[2] = s * a0.z + b2[2]; l[3] = s * a0.w + b2[3];
    l[4] = s * a1.x + b2[4]; l[5] = s * a1.y + b2[5];
    l[6] = s * a1.z + b2[6]; l[7] = s * a1.w + b2[7];
    float m = l[0];
    #pragma unroll
    for (int k = 1; k < NCLS; ++k) m = fmaxf(m, l[k]);
    float sum = 0.f;
    #pragma unroll
    for (int k = 0; k < NCLS; ++k) sum += __expf(l[k] - m);
    float lse = logf(sum) + m;
    float4 r0 = make_float4(l[0] - lse, l[1] - lse, l[2] - lse, l[3] - lse);
    float4 r1 = make_float4(l[4] - lse, l[5] - lse, l[6] - lse, l[7] - lse);
    float4* op = (float4*)(out + (size_t)i * NCLS);
    op[0] = r0; op[1] = r1;
}

extern "C" void kernel_launch(void* const* d_in, const int* in_sizes, int n_in,
                              void* d_out, int out_size, void* d_ws, size_t ws_size,
                              hipStream_t stream) {
    const float* x  = (const float*)d_in[0];
    const int*   ei = (const int*)d_in[1];      // [2, E]: row0 = src, row1 = dst
    const float* W1 = (const float*)d_in[2];
    const float* b1 = (const float*)d_in[3];
    const float* W2 = (const float*)d_in[4];
    const float* b2 = (const float*)d_in[5];
    float* out = (float*)d_out;

    const int* src = ei;
    const int* dst = ei + N_EDGES;

    float* ws = (float*)d_ws;
    const size_t N = N_NODES;
    unsigned* deg = (unsigned*)ws;
    float* dis  = ws + N;
    float* hd1  = ws + 2 * N;
    float* agg1 = ws + 18 * N;
    float* hd2  = ws + 34 * N;
    float* agg2 = ws + 42 * N;

    const int TB = 256;
    int nb_nodes = (N_NODES + TB - 1) / TB;
    int nb_edges = (N_EDGES + TB - 1) / TB;

    k_deg_init<<<nb_nodes, TB, 0, stream>>>(deg);
    k_deg_count<<<nb_edges, TB, 0, stream>>>(dst, deg);
    k_dis<<<nb_nodes, TB, 0, stream>>>(deg, dis);

    k_gemm1<<<(N_NODES + 63) / 64, TB, 0, stream>>>(x, W1, dis, hd1, agg1);

    long long w16 = (long long)N_EDGES * HIDDEN;
    k_scatter16<<<(int)((w16 + TB - 1) / TB), TB, 0, stream>>>(src, dst, hd1, agg1);

    k_layer2<<<nb_nodes, TB, 0, stream>>>(agg1, dis, b1, W2, hd2, agg2);

    long long w8 = (long long)N_EDGES * NCLS;
    k_scatter8<<<(int)((w8 + TB - 1) / TB), TB, 0, stream>>>(src, dst, hd2, agg2);

    k_final<<<nb_nodes, TB, 0, stream>>>(agg2, dis, b2, out);
}